// Round 2
// baseline (81.416 us; speedup 1.0000x reference)
//
#include <hip/hip_runtime.h>

namespace {
constexpr int N   = 64;
constexpr int D   = 32;
constexpr int PD  = 36;   // padded ind row (dwords): measured conflict-free (r1/r2)
constexpr int SHP = 72;   // sh row pad: 72%32==8, same conflict-free residue as
                          // the measured 104 (r11-r14).
constexpr float LOG2E = 1.4426950408889634f;
constexpr float LN2   = 0.6931471805599453f;

typedef float f32x2 __attribute__((ext_vector_type(2)));

#if __has_builtin(__builtin_amdgcn_exp2f)
__device__ __forceinline__ float fexp2(float x) { return __builtin_amdgcn_exp2f(x); }
#else
__device__ __forceinline__ float fexp2(float x) { return exp2f(x); }
#endif
#if __has_builtin(__builtin_amdgcn_rcpf)
__device__ __forceinline__ float frcp(float x) { return __builtin_amdgcn_rcpf(x); }
#else
__device__ __forceinline__ float frcp(float x) { return 1.0f / x; }
#endif
__device__ __forceinline__ void wavebar() {
#if __has_builtin(__builtin_amdgcn_wave_barrier)
    __builtin_amdgcn_wave_barrier();
#endif
}

// r18: MAX RESIDENCY. r17 post-mortem: score loop is stall-bound (issue ~7us
// vs 39us wall); only 4 waves/SIMD resident (4096 waves / 1024 SIMDs, grid ==
// capacity, no replacement). This round targets the HW occupancy cap:
//   grid 1024 (half-b, 32 i-rows), block 512 (8 waves), 4 rows/wave
//   -> 8192 waves = 32 waves/CU = 8/SIMD, ALL resident iff VGPR<=64 and
//      LDS<=40KB. LDS: sh_lds shrunk to 32 rows -> 37632 B (4 blocks/CU =
//      150.5/160 KB). VGPR: __launch_bounds__(512,8) target 64, with an
//      explicit register diet vs r17:
//   - 4-row state: sc2[4]=8, gmask[4]=8 VGPRs (was 8 rows -> 16/16)
//   - score chunked at 8 floats: un/upl live = 16 VGPRs (was 32)
//   - s0 row scalars readfirstlane'd to SGPRs; v4 rows arrive as SGPRs (s_load)
// r4-r6 "spill trap at target 64" was with the old high-pressure structure;
// this structure is designed to fit. If scratch appears -> revert path known.
// Score math unchanged (r14-verified single-exp identity):
//   elup1(a)*elup1(b) = exp2(min(aL,0)+min(bL,0)) * (1+max(aL,0)*ln2) * (1+max(bL,0)*ln2)
__global__ __launch_bounds__(512, 8) void fused(
        const float* __restrict__ feature,
        const float* __restrict__ ind,
        float* __restrict__ out) {
    __shared__ float ind_lds[3][N][PD];   // 27648 B
    __shared__ float s_lds[3][N];         //   768 B
    __shared__ float sh_lds[32][SHP];     //  9216 B   total 37632 B -> 4 blocks/CU

    const int t      = threadIdx.x;
    const int lane   = t & 63;
    const int wave   = t >> 6;
    const int blk    = blockIdx.x;
    const int b      = blk >> 1;
    const int i_base = (blk & 1) << 5;

    // ---- stage indicator: 1536 float4, 3 per thread, coalesced ----
    {
        const float4* src = reinterpret_cast<const float4*>(ind);
#pragma unroll
        for (int idx = t; idx < 3 * N * D / 4; idx += 512) {
            int a = idx >> 9;
            int r = idx & 511;
            int n = r >> 3;
            int k = r & 7;
            *reinterpret_cast<float4*>(&ind_lds[a][n][k * 4]) = src[idx];
        }
    }

    // ---- s[a][n] = feature[b,n,:] . ind[a,n,:] from GLOBAL, overlapped with
    //      staging (single barrier; r13-verified) ----
    if (t < 3 * N) {
        int a = t >> 6, n = t & 63;
        const float4* frow = reinterpret_cast<const float4*>(feature + ((size_t)b * N + n) * D);
        const float4* irow = reinterpret_cast<const float4*>(ind + (a * N + n) * D);
        f32x2 sa2 = {0.f, 0.f};
#pragma unroll
        for (int k = 0; k < 8; ++k) {
            float4 f4 = frow[k];
            float4 i4 = irow[k];
            sa2 = __builtin_elementwise_fma(f32x2{f4.x, f4.y}, f32x2{i4.x, i4.y}, sa2);
            sa2 = __builtin_elementwise_fma(f32x2{f4.z, f4.w}, f32x2{i4.z, i4.w}, sa2);
        }
        s_lds[a][n] = sa2.x + sa2.y;
    }
    __syncthreads();   // the ONLY block barrier

    // wave-uniform row indices (readfirstlane -> SGPR -> s_load addresses)
    int igu[4];
#pragma unroll
    for (int r = 0; r < 4; ++r)
        igu[r] = __builtin_amdgcn_readfirstlane(i_base + wave * 4 + r);

    // ---- gate bitmasks: w-row (ind1[lane]) in VGPRs, a-rows via SCALAR loads
    //      from global ind0 (wave-uniform addr) -> s_load, SGPR operands ----
    unsigned long long gmask[4];
    {
        f32x2 wv[16];
#pragma unroll
        for (int k4 = 0; k4 < 8; ++k4) {
            float4 w4 = *reinterpret_cast<const float4*>(&ind_lds[1][lane][k4 * 4]);
            wv[k4 * 2 + 0] = f32x2{w4.x, w4.y};
            wv[k4 * 2 + 1] = f32x2{w4.z, w4.w};
        }
#pragma unroll
        for (int r = 0; r < 4; ++r) {
            f32x2 ga = {0.f, 0.f};
#pragma unroll
            for (int k4 = 0; k4 < 8; ++k4) {
                float4 a4 = *reinterpret_cast<const float4*>(ind + igu[r] * D + k4 * 4);  // s_load
                ga = __builtin_elementwise_fma(f32x2{a4.x, a4.y}, wv[k4 * 2 + 0], ga);
                ga = __builtin_elementwise_fma(f32x2{a4.z, a4.w}, wv[k4 * 2 + 1], ga);
            }
            gmask[r] = __ballot(ga.x + ga.y > 0.f);
        }
    }

    const float s1Ls = s_lds[1][lane] * LOG2E;
    const f32x2 s1L  = {s1Ls, s1Ls};
    const f32x2 ln2v = {LN2, LN2};
    const f32x2 onev = {1.0f, 1.0f};
    const f32x2 zerv = {0.0f, 0.0f};

    // ---- row scalars held as SGPRs (wave-uniform) ----
    float s0u[4];
#pragma unroll
    for (int r = 0; r < 4; ++r)
        s0u[r] = __uint_as_float(__builtin_amdgcn_readfirstlane(
            __float_as_uint(s_lds[0][i_base + wave * 4 + r] * LOG2E)));

    // ---- score: sign-split packed loop, 4 chunks of 8 d-elements (un/upl
    //      live = 16 VGPRs); v4 rows via SCALAR loads from global ind1 ----
    f32x2 sc2[4] = {{0.f, 0.f}, {0.f, 0.f}, {0.f, 0.f}, {0.f, 0.f}};

#define SCORE_BODY(NEGA, FMAA, AM, FM)                                              \
    {                                                                               \
        const f32x2 amv = {(AM), (AM)};                                             \
        const f32x2 fmv = {(FM), (FM)};                                             \
        f32x2 acc = sc2[r];                                                         \
        _Pragma("unroll")                                                           \
        for (int k4 = 0; k4 < 2; ++k4) {                                            \
            float4 v4 = *reinterpret_cast<const float4*>(                           \
                ind + N * D + igu[r] * D + c * 8 + k4 * 4);    /* s_load */         \
            f32x2 vp[2] = {f32x2{v4.x, v4.y}, f32x2{v4.z, v4.w}};                   \
            _Pragma("unroll")                                                       \
            for (int h = 0; h < 2; ++h) {                                           \
                f32x2 aneg = amv * NEGA[k4 * 2 + h];                                \
                f32x2 A    = __builtin_elementwise_fma(fmv, FMAA[k4 * 2 + h], onev);\
                f32x2 bL   = s1L * vp[h];                                           \
                f32x2 bneg = __builtin_elementwise_min(bL, zerv);                   \
                f32x2 B    = __builtin_elementwise_fma(                             \
                    __builtin_elementwise_max(bL, zerv), ln2v, onev);               \
                f32x2 mn   = aneg + bneg;                                           \
                f32x2 E    = {fexp2(mn.x), fexp2(mn.y)};                            \
                acc = __builtin_elementwise_fma(E * A, B, acc);                     \
            }                                                                       \
        }                                                                           \
        sc2[r] = acc;                                                               \
    }

#pragma unroll
    for (int c = 0; c < 4; ++c) {
        // per-chunk precompute: un = min(u,0), upl = max(u,0)*ln2  (8 f32x2 live)
        f32x2 un[4], upl[4];
#pragma unroll
        for (int k4 = 0; k4 < 2; ++k4) {
            float4 v = *reinterpret_cast<const float4*>(&ind_lds[0][lane][c * 8 + k4 * 4]);
            f32x2 x0 = {v.x, v.y}, x1 = {v.z, v.w};
            f32x2 n0 = __builtin_elementwise_min(x0, zerv);
            f32x2 n1 = __builtin_elementwise_min(x1, zerv);
            un[k4 * 2 + 0]  = n0;
            un[k4 * 2 + 1]  = n1;
            upl[k4 * 2 + 0] = (x0 - n0) * ln2v;
            upl[k4 * 2 + 1] = (x1 - n1) * ln2v;
        }
#pragma unroll
        for (int r = 0; r < 4; ++r) {
            // wave-uniform scalar branch: s_cmp + s_cbranch, zero divergence
            if (s0u[r] >= 0.f) {
                SCORE_BODY(un, upl, s0u[r], s0u[r])
            } else {
                SCORE_BODY(upl, un, s0u[r] * LOG2E, s0u[r] * LN2)
            }
        }
    }
#undef SCORE_BODY

    float score[4];
#pragma unroll
    for (int r = 0; r < 4; ++r) score[r] = sc2[r].x + sc2[r].y;

    // ---- 4-way-ILP wave softmax over j (64 lanes) ----
    float mx[4], e[4], sm[4];
#pragma unroll
    for (int r = 0; r < 4; ++r) mx[r] = score[r];
#pragma unroll
    for (int off = 32; off >= 1; off >>= 1) {
#pragma unroll
        for (int r = 0; r < 4; ++r) mx[r] = fmaxf(mx[r], __shfl_xor(mx[r], off));
    }
#pragma unroll
    for (int r = 0; r < 4; ++r) e[r] = fexp2((score[r] - mx[r]) * LOG2E);
#pragma unroll
    for (int r = 0; r < 4; ++r) sm[r] = e[r];
#pragma unroll
    for (int off = 32; off >= 1; off >>= 1) {
#pragma unroll
        for (int r = 0; r < 4; ++r) sm[r] += __shfl_xor(sm[r], off);
    }
#pragma unroll
    for (int r = 0; r < 4; ++r) {
        const int ig    = i_base + wave * 4 + r;
        const int i_loc = wave * 4 + r;
        const float g   = (float)((gmask[r] >> lane) & 1ull);
        sh_lds[i_loc][lane] = (e[r] * g) * (s_lds[2][ig] * frcp(sm[r]));
    }

    // NO block barrier: wave w wrote sh rows 4w..4w+3 and phase 2's thread t
    // (row t>>4) reads only those rows (same-wave LDS RAW, lgkmcnt-ordered;
    // r13/r14/r16-verified pattern).
    wavebar();

    // ---- phase 2: out[i,:] = sh[i,:] @ ind2; thread = (i_loc, d-quad, j-half) ----
    {
        const int i_loc = t >> 4;
        const int sub   = t & 15;
        const int dq    = sub & 7;
        const int jh    = sub >> 3;
        f32x2 acc0 = {0.f, 0.f}, acc1 = {0.f, 0.f};
#pragma unroll
        for (int jj = 0; jj < 32; jj += 4) {
            int j = jh * 32 + jj;
            float4 sh4 = *reinterpret_cast<const float4*>(&sh_lds[i_loc][j]);
#pragma unroll
            for (int c = 0; c < 4; ++c) {
                float4 v4 = *reinterpret_cast<const float4*>(&ind_lds[2][j + c][dq * 4]);
                float  w  = (&sh4.x)[c];
                f32x2 wvv = {w, w};
                acc0 = __builtin_elementwise_fma(wvv, f32x2{v4.x, v4.y}, acc0);
                acc1 = __builtin_elementwise_fma(wvv, f32x2{v4.z, v4.w}, acc1);
            }
        }
        float4 acc = {acc0.x, acc0.y, acc1.x, acc1.y};
        acc.x += __shfl_xor(acc.x, 8);   // combine j-halves (lanes t, t^8)
        acc.y += __shfl_xor(acc.y, 8);
        acc.z += __shfl_xor(acc.z, 8);
        acc.w += __shfl_xor(acc.w, 8);
        if (jh == 0) {
            *reinterpret_cast<float4*>(out + ((size_t)b * N + i_base + i_loc) * D + dq * 4) = acc;
        }
    }
}
}  // namespace

extern "C" void kernel_launch(void* const* d_in, const int* in_sizes, int n_in,
                              void* d_out, int out_size, void* d_ws, size_t ws_size,
                              hipStream_t stream) {
    const float* feature = (const float*)d_in[0];
    const float* ind     = (const float*)d_in[1];
    float*       out     = (float*)d_out;
    fused<<<1024, 512, 0, stream>>>(feature, ind, out);
}